// Round 2
// 697.418 us; speedup vs baseline: 1.0132x; 1.0132x over previous
//
#include <hip/hip_runtime.h>
#include <hip/hip_cooperative_groups.h>
#include <hip/hip_fp16.h>
#include <cmath>

namespace cg = cooperative_groups;

typedef unsigned short ushort_t;
typedef unsigned int uint_t;

#define N_TOT 30000
#define N0_   18000
#define R_    5
#define E_    600000
#define RN    (R_ * N_TOT)
#define NC_   (N_TOT * 8)        // logits elements
#define NX_   (N_TOT * 128)      // x elements

#define NPW_MAX 15               // max nodes per wave (512-block / 2-per-CU case)

__device__ __forceinline__ ushort_t f2bf(float f) {
    uint_t u = __float_as_uint(f);
    uint_t r = (u + 0x7fffu + ((u >> 16) & 1u)) >> 16;   // RTNE
    return (ushort_t)r;
}
__device__ __forceinline__ float bflo(uint_t v) { return __uint_as_float(v << 16); }
__device__ __forceinline__ float bfhi(uint_t v) { return __uint_as_float(v & 0xffff0000u); }

// ---------------------------------------------------------------------------
// init: u = 1/R, act[0] = 1 (used by fallback path; harmless for coop path)
// ---------------------------------------------------------------------------
__global__ void init_kernel(float* ug, int* act) {
    if (threadIdx.x < 5) ug[threadIdx.x] = 0.2f;
    if (threadIdx.x == 0) act[0] = 1;
}

// ---------------------------------------------------------------------------
// Fused MLP, 8 nodes per 128-thread block + bf16 shadow write (unchanged)
// ---------------------------------------------------------------------------
__global__ __launch_bounds__(128) void mlp_kernel(
    const float* __restrict__ feat0, const float* __restrict__ feat1,
    const float* __restrict__ W0, const float* __restrict__ b0,
    const float* __restrict__ W1, const float* __restrict__ b1,
    const float* __restrict__ Wm1, const float* __restrict__ bm1,
    const float* __restrict__ Wm2, const float* __restrict__ bm2,
    float* __restrict__ xout, ushort_t* __restrict__ xh)
{
    const int j = threadIdx.x;
    const int lane = j & 63, wv_id = j >> 6;
    const int row0 = blockIdx.x * 8;

    __shared__ float sh[8][128];
    __shared__ float red[2][8];

    const bool is0 = (row0 < N0_);
    const float* __restrict__ fbase =
        is0 ? feat0 + (size_t)row0 * 256 : feat1 + (size_t)(row0 - N0_) * 128;
    const float* __restrict__ W = is0 ? W0 : W1;
    const int K = is0 ? 256 : 128;
    const float bias = is0 ? b0[j] : b1[j];

    float acc[8];
    #pragma unroll
    for (int p = 0; p < 8; ++p) acc[p] = bias;

    for (int k = 0; k < K; k += 4) {
        float w0 = W[(k + 0) * 128 + j];
        float w1 = W[(k + 1) * 128 + j];
        float w2 = W[(k + 2) * 128 + j];
        float w3 = W[(k + 3) * 128 + j];
        #pragma unroll
        for (int p = 0; p < 8; ++p) {
            const float4 f4 = *(const float4*)(fbase + (size_t)p * K + k);
            acc[p] = fmaf(f4.x, w0, acc[p]);
            acc[p] = fmaf(f4.y, w1, acc[p]);
            acc[p] = fmaf(f4.z, w2, acc[p]);
            acc[p] = fmaf(f4.w, w3, acc[p]);
        }
    }
    #pragma unroll
    for (int p = 0; p < 8; ++p) sh[p][j] = acc[p];
    __syncthreads();

    float t1[8];
    #pragma unroll
    for (int p = 0; p < 8; ++p) t1[p] = bm1[j];
    for (int k = 0; k < 128; k += 4) {
        float w0 = Wm1[(k + 0) * 128 + j];
        float w1 = Wm1[(k + 1) * 128 + j];
        float w2 = Wm1[(k + 2) * 128 + j];
        float w3 = Wm1[(k + 3) * 128 + j];
        #pragma unroll
        for (int p = 0; p < 8; ++p) {
            const float4 f4 = *(const float4*)(&sh[p][k]);
            t1[p] = fmaf(f4.x, w0, t1[p]);
            t1[p] = fmaf(f4.y, w1, t1[p]);
            t1[p] = fmaf(f4.z, w2, t1[p]);
            t1[p] = fmaf(f4.w, w3, t1[p]);
        }
    }

    float mean[8];
    {
        #pragma unroll
        for (int p = 0; p < 8; ++p) {
            float s = t1[p];
            for (int o = 32; o > 0; o >>= 1) s += __shfl_down(s, o, 64);
            if (lane == 0) red[wv_id][p] = s;
        }
        __syncthreads();
        #pragma unroll
        for (int p = 0; p < 8; ++p) mean[p] = (red[0][p] + red[1][p]) * (1.0f / 128.0f);
        __syncthreads();
        #pragma unroll
        for (int p = 0; p < 8; ++p) {
            float d = t1[p] - mean[p];
            float s = d * d;
            for (int o = 32; o > 0; o >>= 1) s += __shfl_down(s, o, 64);
            if (lane == 0) red[wv_id][p] = s;
        }
        __syncthreads();
    }
    #pragma unroll
    for (int p = 0; p < 8; ++p) {
        float var = (red[0][p] + red[1][p]) * (1.0f / 128.0f);
        float z = fmaxf((t1[p] - mean[p]) / sqrtf(var + 1e-5f), 0.0f);
        t1[p] = z;
    }
    __syncthreads();
    #pragma unroll
    for (int p = 0; p < 8; ++p) sh[p][j] = t1[p];
    __syncthreads();

    float t2[8];
    #pragma unroll
    for (int p = 0; p < 8; ++p) t2[p] = bm2[j];
    for (int k = 0; k < 128; k += 4) {
        float w0 = Wm2[(k + 0) * 128 + j];
        float w1 = Wm2[(k + 1) * 128 + j];
        float w2 = Wm2[(k + 2) * 128 + j];
        float w3 = Wm2[(k + 3) * 128 + j];
        #pragma unroll
        for (int p = 0; p < 8; ++p) {
            const float4 f4 = *(const float4*)(&sh[p][k]);
            t2[p] = fmaf(f4.x, w0, t2[p]);
            t2[p] = fmaf(f4.y, w1, t2[p]);
            t2[p] = fmaf(f4.z, w2, t2[p]);
            t2[p] = fmaf(f4.w, w3, t2[p]);
        }
    }

    float mu[8];
    {
        #pragma unroll
        for (int p = 0; p < 8; ++p) {
            float s = t2[p];
            for (int o = 32; o > 0; o >>= 1) s += __shfl_down(s, o, 64);
            if (lane == 0) red[wv_id][p] = s;
        }
        __syncthreads();
        #pragma unroll
        for (int p = 0; p < 8; ++p) mu[p] = (red[0][p] + red[1][p]) * (1.0f / 128.0f);
        __syncthreads();
        #pragma unroll
        for (int p = 0; p < 8; ++p) {
            float d = t2[p] - mu[p];
            float s = d * d;
            for (int o = 32; o > 0; o >>= 1) s += __shfl_down(s, o, 64);
            if (lane == 0) red[wv_id][p] = s;
        }
        __syncthreads();
    }
    #pragma unroll
    for (int p = 0; p < 8; ++p) {
        float sd = sqrtf((red[0][p] + red[1][p]) * (1.0f / 127.0f));
        float r = (t2[p] - mu[p]) / sd;
        if (!(fabsf(r) <= 3.402823466e38f)) {
            r = (r != r) ? 0.0f : ((r > 0.0f) ? 3.402823466e38f : -3.402823466e38f);
        }
        xout[(size_t)(row0 + p) * 128 + j] = r;
        xh[(size_t)(row0 + p) * 128 + j] = f2bf(r);
    }
}

// ---------------------------------------------------------------------------
// preprocessing (unchanged)
// ---------------------------------------------------------------------------
__global__ void deg_kernel(const int* __restrict__ src, const int* __restrict__ rel,
                           int* __restrict__ deg_i)
{
    int e = blockIdx.x * 256 + threadIdx.x;
    if (e >= E_) return;
    atomicAdd(&deg_i[rel[e] * N_TOT + src[e]], 1);
}

__global__ void dinv_kernel(const int* __restrict__ deg_i, float* __restrict__ dinv)
{
    int i = blockIdx.x * 256 + threadIdx.x;
    if (i >= RN) return;
    int dg = deg_i[i];
    dinv[i] = (dg > 0) ? 1.0f / sqrtf((float)dg) : 0.0f;
}

__global__ __launch_bounds__(1024) void scan_kernel(const int* __restrict__ cnt,
                                                    int* __restrict__ rp)
{
    __shared__ int wsum[16];
    __shared__ int s_carry;
    const int t = threadIdx.x, lane = t & 63, w = t >> 6;
    if (t == 0) s_carry = 0;
    __syncthreads();
    const int CH = 8192;
    for (int base = 0; base < RN; base += CH) {
        int v[8]; int s = 0;
        const int i0 = base + t * 8;
        #pragma unroll
        for (int i = 0; i < 8; ++i) { int ii = i0 + i; v[i] = (ii < RN) ? cnt[ii] : 0; s += v[i]; }
        int sc = s;
        #pragma unroll
        for (int o = 1; o < 64; o <<= 1) { int tmp = __shfl_up(sc, o, 64); if (lane >= o) sc += tmp; }
        if (lane == 63) wsum[w] = sc;
        __syncthreads();
        int woff = 0;
        for (int i = 0; i < w; ++i) woff += wsum[i];
        int run = s_carry + woff + (sc - s);
        #pragma unroll
        for (int i = 0; i < 8; ++i) { int ii = i0 + i; if (ii < RN) rp[ii] = run; run += v[i]; }
        int chunk_total = woff + sc;   // valid for t==1023
        __syncthreads();
        if (t == 1023) s_carry += chunk_total;
        __syncthreads();
    }
    if (threadIdx.x == 0) rp[RN] = s_carry;
}

__global__ void scatter_kernel(const int* __restrict__ src, const int* __restrict__ dst,
                               const int* __restrict__ rel, const int* __restrict__ rp,
                               int* __restrict__ fill, const int* __restrict__ deg_i,
                               const float* __restrict__ dinv,
                               int* __restrict__ csr_dst, float* __restrict__ csr_w,
                               float* __restrict__ csr_edinv)
{
    int e = blockIdx.x * 256 + threadIdx.x;
    if (e >= E_) return;
    int s = src[e], r = rel[e], d = dst[e];
    int key = r * N_TOT + s;
    int pos = rp[key] + atomicAdd(&fill[key], 1);
    csr_dst[pos] = d;
    csr_w[pos] = 1.0f / (float)deg_i[key];
    csr_edinv[pos] = dinv[key] * dinv[r * N_TOT + d];
}

// ---------------------------------------------------------------------------
// Persistent cooperative loop kernel: ONE edge-gather pass per outer
// iteration. Per-relation message accumulators are packed as fp16 pairs
// (__half2) to halve persistent VGPR state (75 regs for NPW_MAX=15).
// Mirror descent is replayed redundantly (identically) by every lane.
// ---------------------------------------------------------------------------
__global__ __launch_bounds__(256, 3) void loop_kernel(
    float* __restrict__ x, ushort_t* __restrict__ xh0, ushort_t* __restrict__ xh1,
    const int* __restrict__ rp, const int* __restrict__ csr_dst,
    const float* __restrict__ csr_edinv, const float* __restrict__ csr_w,
    float* __restrict__ accbuf, float* __restrict__ ug, int npw)
{
    cg::grid_group grid = cg::this_grid();
    const int lane = threadIdx.x & 63;
    const int wv = threadIdx.x >> 6;
    const int wid = blockIdx.x * 4 + wv;
    __shared__ float sacc[4][10];

    float u0 = 0.2f, u1 = 0.2f, u2 = 0.2f, u3 = 0.2f, u4 = 0.2f;
    float c_l1 = 1.0f;
    bool active = true;

    const ushort_t* xh_a = xh0;   // gather source this iteration
    ushort_t* xh_b = xh1;         // shadow written this iteration

    for (int k = 0; k < 8; ++k) {
        __half2 m[NPW_MAX][5];                 // packed per-node msg state
        float na[5] = {0, 0, 0, 0, 0};
        float ea[5] = {0, 0, 0, 0, 0};

        if (active) {
            #pragma unroll
            for (int i = 0; i < NPW_MAX; ++i) {
                const int n = wid * npw + i;
                if (i < npw && n < N_TOT) {
                    const uint_t vs = ((const uint_t*)(xh_a + (size_t)n * 128))[lane];
                    const float sx = bflo(vs), sy = bfhi(vs);
                    const float pp = fmaf(sx, sx, sy * sy);
                    #pragma unroll
                    for (int r = 0; r < 5; ++r) {
                        const int e0 = rp[r * N_TOT + n];
                        const int e1 = rp[r * N_TOT + n + 1];
                        if (e1 > e0) na[r] += pp;
                        float d0 = 0.0f, d1 = 0.0f;
                        float mxa = 0.0f, mya = 0.0f, mxb = 0.0f, myb = 0.0f;
                        int e = e0;
                        for (; e + 2 <= e1; e += 2) {
                            const int dn0 = csr_dst[e];
                            const int dn1 = csr_dst[e + 1];
                            const float ed0 = csr_edinv[e];
                            const float ed1 = csr_edinv[e + 1];
                            const float cw0 = csr_w[e];
                            const float cw1 = csr_w[e + 1];
                            const uint_t v0 = ((const uint_t*)(xh_a + (size_t)dn0 * 128))[lane];
                            const uint_t v1 = ((const uint_t*)(xh_a + (size_t)dn1 * 128))[lane];
                            const float x0 = bflo(v0), y0 = bfhi(v0);
                            const float x1 = bflo(v1), y1 = bfhi(v1);
                            d0 = fmaf(ed0, fmaf(sx, x0, sy * y0), d0);
                            d1 = fmaf(ed1, fmaf(sx, x1, sy * y1), d1);
                            mxa = fmaf(cw0, x0, mxa); mya = fmaf(cw0, y0, mya);
                            mxb = fmaf(cw1, x1, mxb); myb = fmaf(cw1, y1, myb);
                        }
                        if (e < e1) {
                            const int dn0 = csr_dst[e];
                            const float ed0 = csr_edinv[e];
                            const float cw0 = csr_w[e];
                            const uint_t v0 = ((const uint_t*)(xh_a + (size_t)dn0 * 128))[lane];
                            const float x0 = bflo(v0), y0 = bfhi(v0);
                            d0 = fmaf(ed0, fmaf(sx, x0, sy * y0), d0);
                            mxa = fmaf(cw0, x0, mxa); mya = fmaf(cw0, y0, mya);
                        }
                        ea[r] += d0 + d1;
                        m[i][r] = __floats2half2_rn(mxa + mxb, mya + myb);
                    }
                }
            }
            // block reduction of tv partials, one atomicAdd set per block
            #pragma unroll
            for (int r = 0; r < 5; ++r) {
                float a = na[r], b2 = ea[r];
                for (int o = 32; o > 0; o >>= 1) {
                    a += __shfl_down(a, o, 64);
                    b2 += __shfl_down(b2, o, 64);
                }
                if (lane == 0) { sacc[wv][r] = a; sacc[wv][5 + r] = b2; }
            }
            __syncthreads();
            if (threadIdx.x < 10) {
                float t = sacc[0][threadIdx.x] + sacc[1][threadIdx.x] +
                          sacc[2][threadIdx.x] + sacc[3][threadIdx.x];
                atomicAdd(&accbuf[k * 16 + threadIdx.x], t);
            }
        }
        grid.sync();

        bool still = false;
        if (active) {
            float wr[5], l1 = 0.0f;
            #pragma unroll
            for (int r = 0; r < 5; ++r) {
                const float nt = __hip_atomic_load(&accbuf[k * 16 + r],
                                                   __ATOMIC_RELAXED, __HIP_MEMORY_SCOPE_AGENT);
                const float et = __hip_atomic_load(&accbuf[k * 16 + 5 + r],
                                                   __ATOMIC_RELAXED, __HIP_MEMORY_SCOPE_AGENT);
                wr[r] = (nt - et) * (1.0f / 30000.0f);
                l1 += fabsf(wr[r]);
            }
            if (k == 0) c_l1 = l1;

            // mirror descent, replicated identically in every lane
            const float fi = l1 + 3.0f;
            float v0 = u0, v1 = u1, v2 = u2, v3 = u3, v4 = u4;
            bool mact = true;
            for (int t = 1; t <= 20; ++t) {
                const float T = sqrtf(3.2188758248682006f / ((float)t * fi * fi));
                const float t0 = v0 * expf(-T * (3.0f * v0 + wr[0]));
                const float t1 = v1 * expf(-T * (3.0f * v1 + wr[1]));
                const float t2 = v2 * expf(-T * (3.0f * v2 + wr[2]));
                const float t3 = v3 * expf(-T * (3.0f * v3 + wr[3]));
                const float t4 = v4 * expf(-T * (3.0f * v4 + wr[4]));
                const float inv = 1.0f / (t0 + t1 + t2 + t3 + t4);
                const float n0 = t0 * inv, n1 = t1 * inv, n2 = t2 * inv,
                            n3 = t3 * inv, n4 = t4 * inv;
                const float dq = (v0 - n0) * (v0 - n0) + (v1 - n1) * (v1 - n1) +
                                 (v2 - n2) * (v2 - n2) + (v3 - n3) * (v3 - n3) +
                                 (v4 - n4) * (v4 - n4);
                if (mact) { v0 = n0; v1 = n1; v2 = n2; v3 = n3; v4 = n4; }
                mact = mact && (sqrtf(dq) >= 1e-3f);
            }
            u0 = v0; u1 = v1; u2 = v2; u3 = v3; u4 = v4;
            still = (l1 / c_l1 >= 0.3f);
        }

        if (still) {
            const float ci = 1.0f / 21.0f, cb = 20.0f / 21.0f;
            #pragma unroll
            for (int i = 0; i < NPW_MAX; ++i) {
                const int n = wid * npw + i;
                if (i < npw && n < N_TOT) {
                    const float2 m0 = __half22float2(m[i][0]);
                    const float2 m1 = __half22float2(m[i][1]);
                    const float2 m2 = __half22float2(m[i][2]);
                    const float2 m3 = __half22float2(m[i][3]);
                    const float2 m4 = __half22float2(m[i][4]);
                    const float sm_x = u0 * m0.x + u1 * m1.x + u2 * m2.x +
                                       u3 * m3.x + u4 * m4.x;
                    const float sm_y = u0 * m0.y + u1 * m1.y + u2 * m2.y +
                                       u3 * m3.y + u4 * m4.y;
                    float2* xp = (float2*)(x + (size_t)n * 128);
                    const float2 xs = xp[lane];
                    const float nx_ = fmaf(cb, sm_x, xs.x * ci);
                    const float ny_ = fmaf(cb, sm_y, xs.y * ci);
                    xp[lane] = make_float2(nx_, ny_);
                    ((uint_t*)(xh_b + (size_t)n * 128))[lane] =
                        ((uint_t)f2bf(ny_) << 16) | (uint_t)f2bf(nx_);
                }
            }
        }
        active = still;
        const ushort_t* tp = xh_a; xh_a = xh_b; xh_b = (ushort_t*)tp;
        grid.sync();
    }

    if (blockIdx.x == 0 && threadIdx.x == 0) {
        ug[0] = u0; ug[1] = u1; ug[2] = u2; ug[3] = u3; ug[4] = u4;
    }
}

// ---------------------------------------------------------------------------
// Fallback path kernels (proven 697 µs structure) — used only if the
// cooperative launch cannot run.
// ---------------------------------------------------------------------------
__global__ __launch_bounds__(256) void tv_kernel(
    const ushort_t* __restrict__ xh, const int* __restrict__ rp,
    const int* __restrict__ csr_dst, const float* __restrict__ csr_edinv,
    const int* __restrict__ act, int k, float* __restrict__ accbuf)
{
    if (act[k] == 0) return;
    const int lane = threadIdx.x & 63;
    const int wv = threadIdx.x >> 6;
    const int wid = blockIdx.x * 4 + wv;
    const int nw = gridDim.x * 4;
    float na[5] = {0, 0, 0, 0, 0};
    float ea[5] = {0, 0, 0, 0, 0};
    for (int n = wid; n < N_TOT; n += nw) {
        const uint_t vs = ((const uint_t*)(xh + (size_t)n * 128))[lane];
        const float sx = bflo(vs), sy = bfhi(vs);
        const float pp = fmaf(sx, sx, sy * sy);
        #pragma unroll
        for (int r = 0; r < 5; ++r) {
            const int e0 = rp[r * N_TOT + n];
            const int e1 = rp[r * N_TOT + n + 1];
            if (e1 > e0) na[r] += pp;
            float acc0 = 0.0f, acc1 = 0.0f;
            int e = e0;
            for (; e + 2 <= e1; e += 2) {
                const int dn0 = csr_dst[e];
                const int dn1 = csr_dst[e + 1];
                const float w0 = csr_edinv[e];
                const float w1 = csr_edinv[e + 1];
                const uint_t v0 = ((const uint_t*)(xh + (size_t)dn0 * 128))[lane];
                const uint_t v1 = ((const uint_t*)(xh + (size_t)dn1 * 128))[lane];
                acc0 = fmaf(w0, fmaf(sx, bflo(v0), sy * bfhi(v0)), acc0);
                acc1 = fmaf(w1, fmaf(sx, bflo(v1), sy * bfhi(v1)), acc1);
            }
            if (e < e1) {
                const int dn0 = csr_dst[e];
                const float w0 = csr_edinv[e];
                const uint_t v0 = ((const uint_t*)(xh + (size_t)dn0 * 128))[lane];
                acc0 = fmaf(w0, fmaf(sx, bflo(v0), sy * bfhi(v0)), acc0);
            }
            ea[r] += acc0 + acc1;
        }
    }
    __shared__ float sacc[4][10];
    #pragma unroll
    for (int r = 0; r < 5; ++r) {
        float a = na[r], b2 = ea[r];
        for (int o = 32; o > 0; o >>= 1) {
            a += __shfl_down(a, o, 64);
            b2 += __shfl_down(b2, o, 64);
        }
        if (lane == 0) { sacc[wv][r] = a; sacc[wv][5 + r] = b2; }
    }
    __syncthreads();
    if (threadIdx.x < 10) {
        float t = sacc[0][threadIdx.x] + sacc[1][threadIdx.x] +
                  sacc[2][threadIdx.x] + sacc[3][threadIdx.x];
        atomicAdd(&accbuf[k * 16 + threadIdx.x], t);
    }
}

__global__ void scalar_kernel(const float* __restrict__ accbuf, float* __restrict__ ug,
                              float* __restrict__ c_l1, int* __restrict__ act, int k)
{
    if (blockIdx.x != 0 || threadIdx.x >= 8) return;
    const int r = threadIdx.x;
    const int a = act[k];
    float w = (r < 5) ? (accbuf[k * 16 + r] - accbuf[k * 16 + 5 + r]) * (1.0f / 30000.0f)
                      : 0.0f;
    float l1 = fabsf(w);
    for (int o = 4; o > 0; o >>= 1) l1 += __shfl_xor(l1, o, 8);
    if (k == 0 && r == 0) c_l1[0] = l1;
    if (!a) { if (r == 0) act[k + 1] = 0; return; }
    float u = (r < 5) ? ug[r] : 0.0f;
    const float fi = l1 + 3.0f;
    bool mact = true;
    for (int t = 1; t <= 20; ++t) {
        float T = sqrtf(3.2188758248682006f / ((float)t * fi * fi));
        float ta = u * expf(-T * (3.0f * u + w));
        float ssum = ta;
        for (int o = 4; o > 0; o >>= 1) ssum += __shfl_xor(ssum, o, 8);
        float un = ta / ssum;
        float d0 = u - un;
        float dq = d0 * d0;
        for (int o = 4; o > 0; o >>= 1) dq += __shfl_xor(dq, o, 8);
        if (mact) u = un;
        mact = mact && (sqrtf(dq) >= 1e-3f);
    }
    if (r < 5) ug[r] = u;
    if (r == 0) act[k + 1] = (l1 / c_l1[0] >= 0.3f) ? 1 : 0;
}

__global__ __launch_bounds__(256) void msg_upd_kernel(
    float* __restrict__ x, const ushort_t* __restrict__ xh_in,
    ushort_t* __restrict__ xh_out,
    const int* __restrict__ rp, const int* __restrict__ csr_dst,
    const float* __restrict__ csr_w, const float* __restrict__ ug,
    const int* __restrict__ act, int k)
{
    if (act[k + 1] == 0) return;
    const int lane = threadIdx.x & 63;
    const int wid = blockIdx.x * 4 + (threadIdx.x >> 6);
    const int nw = gridDim.x * 4;
    const float u0 = ug[0], u1 = ug[1], u2 = ug[2], u3 = ug[3], u4 = ug[4];
    for (int n = wid; n < N_TOT; n += nw) {
        float ax0 = 0.0f, ay0 = 0.0f, ax1 = 0.0f, ay1 = 0.0f;
        #pragma unroll
        for (int r = 0; r < 5; ++r) {
            const float ur = (r == 0) ? u0 : (r == 1) ? u1 : (r == 2) ? u2 : (r == 3) ? u3 : u4;
            const int e0 = rp[r * N_TOT + n];
            const int e1 = rp[r * N_TOT + n + 1];
            int e = e0;
            for (; e + 2 <= e1; e += 2) {
                const float w0 = ur * csr_w[e];
                const float w1 = ur * csr_w[e + 1];
                const int dn0 = csr_dst[e];
                const int dn1 = csr_dst[e + 1];
                const uint_t v0 = ((const uint_t*)(xh_in + (size_t)dn0 * 128))[lane];
                const uint_t v1 = ((const uint_t*)(xh_in + (size_t)dn1 * 128))[lane];
                ax0 = fmaf(w0, bflo(v0), ax0);
                ay0 = fmaf(w0, bfhi(v0), ay0);
                ax1 = fmaf(w1, bflo(v1), ax1);
                ay1 = fmaf(w1, bfhi(v1), ay1);
            }
            if (e < e1) {
                const float w0 = ur * csr_w[e];
                const int dn0 = csr_dst[e];
                const uint_t v0 = ((const uint_t*)(xh_in + (size_t)dn0 * 128))[lane];
                ax0 = fmaf(w0, bflo(v0), ax0);
                ay0 = fmaf(w0, bfhi(v0), ay0);
            }
        }
        const float ci = 1.0f / 21.0f, cb = 20.0f / 21.0f;
        float2* xp = (float2*)(x + (size_t)n * 128);
        const float2 xs = xp[lane];
        const float nx_ = fmaf(cb, ax0 + ax1, xs.x * ci);
        const float ny_ = fmaf(cb, ay0 + ay1, xs.y * ci);
        xp[lane] = make_float2(nx_, ny_);
        ((uint_t*)(xh_out + (size_t)n * 128))[lane] =
            ((uint_t)f2bf(ny_) << 16) | (uint_t)f2bf(nx_);
    }
}

// ---------------------------------------------------------------------------
// epilogue: logits = x@Wout + bout ; write logits, x, u (unchanged)
// ---------------------------------------------------------------------------
__global__ __launch_bounds__(256) void final_kernel(const float* __restrict__ x,
                                                    const float* __restrict__ Wout,
                                                    const float* __restrict__ bout,
                                                    const float* __restrict__ ug,
                                                    float* __restrict__ out)
{
    const int nl = threadIdx.x >> 7;
    const int n = blockIdx.x * 2 + nl;
    const int j = threadIdx.x & 127;
    const int lane = threadIdx.x & 63;
    const int wv = threadIdx.x >> 6;
    float xv = x[(size_t)n * 128 + j];
    out[(size_t)NC_ + (size_t)n * 128 + j] = xv;
    float p[8];
    #pragma unroll
    for (int c = 0; c < 8; ++c) p[c] = xv * Wout[j * 8 + c];
    #pragma unroll
    for (int c = 0; c < 8; ++c)
        for (int o = 32; o > 0; o >>= 1) p[c] += __shfl_down(p[c], o, 64);
    __shared__ float sp[4][8];
    if (lane == 0) {
        #pragma unroll
        for (int c = 0; c < 8; ++c) sp[wv][c] = p[c];
    }
    __syncthreads();
    if (j < 8) {
        int c = j;
        out[(size_t)n * 8 + c] = bout[c] + sp[2 * nl][c] + sp[2 * nl + 1][c];
    }
    if (blockIdx.x == 0 && threadIdx.x < 5)
        out[(size_t)NC_ + (size_t)NX_ + threadIdx.x] = ug[threadIdx.x];
}

// ---------------------------------------------------------------------------
extern "C" void kernel_launch(void* const* d_in, const int* in_sizes, int n_in,
                              void* d_out, int out_size, void* d_ws, size_t ws_size,
                              hipStream_t stream)
{
    const float* feat0 = (const float*)d_in[0];
    const float* feat1 = (const float*)d_in[1];
    const float* W0   = (const float*)d_in[2];
    const float* b0   = (const float*)d_in[3];
    const float* W1   = (const float*)d_in[4];
    const float* b1   = (const float*)d_in[5];
    const float* Wm1  = (const float*)d_in[6];
    const float* bm1  = (const float*)d_in[7];
    const float* Wm2  = (const float*)d_in[8];
    const float* bm2  = (const float*)d_in[9];
    const float* Wout = (const float*)d_in[10];
    const float* bout = (const float*)d_in[11];
    const int* src = (const int*)d_in[12];
    const int* dst = (const int*)d_in[13];
    const int* rel = (const int*)d_in[14];
    float* out = (float*)d_out;

    char* p = (char*)d_ws;
    auto alloc = [&](size_t bytes) { char* q = p; p += (bytes + 255) & ~(size_t)255; return q; };
    float*    xbuf      = (float*)   alloc((size_t)NX_ * 4);
    ushort_t* xh0       = (ushort_t*)alloc((size_t)NX_ * 2);
    ushort_t* xh1       = (ushort_t*)alloc((size_t)NX_ * 2);
    int*      deg_i     = (int*)     alloc((size_t)RN * 4);
    float*    dinv      = (float*)   alloc((size_t)RN * 4);
    int*      rp        = (int*)     alloc(((size_t)RN + 1) * 4);
    int*      fill      = (int*)     alloc((size_t)RN * 4);
    int*      csr_dst   = (int*)     alloc((size_t)E_ * 4);
    float*    csr_w     = (float*)   alloc((size_t)E_ * 4);
    float*    csr_edinv = (float*)   alloc((size_t)E_ * 4);
    float*    accbuf    = (float*)   alloc(128 * 4);
    float*    ug        = (float*)   alloc(64);
    float*    c_l1      = (float*)   alloc(64);
    int*      act       = (int*)     alloc(64);

    hipMemsetAsync(deg_i, 0, (size_t)RN * 4, stream);
    hipMemsetAsync(fill, 0, (size_t)RN * 4, stream);
    hipMemsetAsync(accbuf, 0, 128 * 4, stream);
    init_kernel<<<1, 64, 0, stream>>>(ug, act);

    mlp_kernel<<<N_TOT / 8, 128, 0, stream>>>(feat0, feat1, W0, b0, W1, b1,
                                              Wm1, bm1, Wm2, bm2, xbuf, xh0);

    deg_kernel<<<(E_ + 255) / 256, 256, 0, stream>>>(src, rel, deg_i);
    dinv_kernel<<<(RN + 255) / 256, 256, 0, stream>>>(deg_i, dinv);
    scan_kernel<<<1, 1024, 0, stream>>>(deg_i, rp);
    scatter_kernel<<<(E_ + 255) / 256, 256, 0, stream>>>(src, dst, rel, rp, fill,
                                                         deg_i, dinv,
                                                         csr_dst, csr_w, csr_edinv);

    // --- cooperative fused loop, sized from actual occupancy -------------
    int launched = 0;
    int maxB = 0;
    hipError_t qe = hipOccupancyMaxActiveBlocksPerMultiprocessor(
        &maxB, reinterpret_cast<const void*>(loop_kernel), 256, 0);
    if (qe == hipSuccess && maxB >= 2) {
        int mb = maxB > 4 ? 4 : maxB;
        int blocks = mb * 256;                 // 256 CUs on MI355X
        int nwaves = blocks * 4;
        int npw = (N_TOT + nwaves - 1) / nwaves;   // <= 15 for blocks >= 512
        void* args[10];
        args[0] = (void*)&xbuf;
        args[1] = (void*)&xh0;
        args[2] = (void*)&xh1;
        args[3] = (void*)&rp;
        args[4] = (void*)&csr_dst;
        args[5] = (void*)&csr_edinv;
        args[6] = (void*)&csr_w;
        args[7] = (void*)&accbuf;
        args[8] = (void*)&ug;
        args[9] = (void*)&npw;
        hipError_t le = hipLaunchCooperativeKernel(loop_kernel, dim3(blocks),
                                                   dim3(256), args, 0, stream);
        if (le == hipSuccess) launched = 1;
    }

    if (!launched) {
        // fallback: proven 3-kernel-per-iteration path
        ushort_t* ha = xh0;
        ushort_t* hb = xh1;
        for (int k = 0; k < 8; ++k) {
            tv_kernel<<<2048, 256, 0, stream>>>(ha, rp, csr_dst, csr_edinv, act, k, accbuf);
            scalar_kernel<<<1, 64, 0, stream>>>(accbuf, ug, c_l1, act, k);
            msg_upd_kernel<<<2048, 256, 0, stream>>>(xbuf, ha, hb, rp, csr_dst, csr_w,
                                                     ug, act, k);
            ushort_t* t = ha; ha = hb; hb = t;
        }
    }

    final_kernel<<<N_TOT / 2, 256, 0, stream>>>(xbuf, Wout, bout, ug, out);
}